// Round 2
// baseline (693.213 us; speedup 1.0000x reference)
//
#include <hip/hip_runtime.h>
#include <math.h>

// Problem constants (from reference): hidden [2,32,1024] f32,
// encoder_outputs [32,4096,1024] f32, mask [32,4096] int.
// Outputs: context [32,1024] f32 then attn [32,4096] f32, concatenated.
#define B_ 32
#define S_ 4096
#define H_ 1024
#define NBLK 32                               // blocks per batch in pass 1
#define ROWS_PER_BLOCK (S_ / NBLK)            // 128
#define NWAVE 4
#define ROWS_PER_WAVE (ROWS_PER_BLOCK / NWAVE) // 32
#define CHUNK 4                                // rows processed per chunk
#define NCHUNK (ROWS_PER_WAVE / CHUNK)         // 8
#define NEG_INF_ -1.0e9f

// Pass 1: one pass over encoder_outputs. Each wave streams 32 rows in
// chunks of 4 held in registers: 16 independent global_load_dwordx4 per
// chunk (MLP), 4 partial dots, 6-stage butterfly on 4 independent values
// per stage (amortized cross-lane latency), one online-softmax rescale
// per chunk. Block combines 4 waves in LDS, emits (M,L,ctx[1024]).
__global__ __launch_bounds__(256, 4) void attn_pass1(
    const float* __restrict__ hidden,   // [2,B,H] — use layer 1 (last)
    const float* __restrict__ enc,      // [B,S,H]
    const int*   __restrict__ mask,     // [B,S]
    float* __restrict__ scores,         // raw scores -> attn slot of d_out [B,S]
    float* __restrict__ part_ctx,       // ws: [B*NBLK, H]
    float* __restrict__ part_ml)        // ws: [B*NBLK, 2] = (M, L)
{
    const int blk  = blockIdx.x;        // 0 .. B*NBLK-1
    const int b    = blk >> 5;          // / NBLK
    const int cb   = blk & 31;          // % NBLK
    const int tid  = threadIdx.x;
    const int wave = tid >> 6;
    const int lane = tid & 63;

    // h fragment: lane holds elems {4L..4L+3, 256+4L.., 512+4L.., 768+4L..}
    const float4* h4 = (const float4*)(hidden + (size_t)(B_ + b) * H_); // layer -1
    const float4 hf0 = h4[lane];
    const float4 hf1 = h4[lane + 64];
    const float4 hf2 = h4[lane + 128];
    const float4 hf3 = h4[lane + 192];

    float m = -INFINITY;
    float l = 0.0f;
    float4 c0 = {0.f, 0.f, 0.f, 0.f};
    float4 c1 = c0, c2 = c0, c3 = c0;
    float myscore = 0.0f;               // lane r (r<32) keeps row row0+r's score

    const int    row0  = cb * ROWS_PER_BLOCK + wave * ROWS_PER_WAVE;
    const float* encb  = enc  + (size_t)b * S_ * H_;
    const int*   maskb = mask + (size_t)b * S_;

    for (int k = 0; k < NCHUNK; ++k) {
        const int sbase = row0 + k * CHUNK;

        // ---- load 4 rows (16 independent 16B loads) ----
        float4 r[CHUNK][4];
        #pragma unroll
        for (int c = 0; c < CHUNK; ++c) {
            const float4* row4 = (const float4*)(encb + (size_t)(sbase + c) * H_);
            r[c][0] = row4[lane];
            r[c][1] = row4[lane + 64];
            r[c][2] = row4[lane + 128];
            r[c][3] = row4[lane + 192];
        }

        // ---- partial dots ----
        float pd[CHUNK];
        #pragma unroll
        for (int c = 0; c < CHUNK; ++c) {
            float d = r[c][0].x * hf0.x + r[c][0].y * hf0.y + r[c][0].z * hf0.z + r[c][0].w * hf0.w;
            d += r[c][1].x * hf1.x + r[c][1].y * hf1.y + r[c][1].z * hf1.z + r[c][1].w * hf1.w;
            d += r[c][2].x * hf2.x + r[c][2].y * hf2.y + r[c][2].z * hf2.z + r[c][2].w * hf2.w;
            d += r[c][3].x * hf3.x + r[c][3].y * hf3.y + r[c][3].z * hf3.z + r[c][3].w * hf3.w;
            pd[c] = d;
        }

        // ---- butterfly reduce, 4 independent values per stage ----
        #pragma unroll
        for (int off = 32; off >= 1; off >>= 1) {
            #pragma unroll
            for (int c = 0; c < CHUNK; ++c)
                pd[c] += __shfl_xor(pd[c], off, 64);
        }

        // ---- mask -> scores ----
        float sc[CHUNK];
        #pragma unroll
        for (int c = 0; c < CHUNK; ++c) {
            sc[c] = (maskb[sbase + c] != 0) ? pd[c] : NEG_INF_;
            if (lane == k * CHUNK + c) myscore = sc[c];
        }

        // ---- online softmax update (once per chunk) ----
        float cmax = fmaxf(fmaxf(sc[0], sc[1]), fmaxf(sc[2], sc[3]));
        const float newm  = fmaxf(m, cmax);
        const float scale = __expf(m - newm);      // exp(-inf)=0 handles init
        float p[CHUNK];
        float psum = 0.0f;
        #pragma unroll
        for (int c = 0; c < CHUNK; ++c) { p[c] = __expf(sc[c] - newm); psum += p[c]; }
        l = l * scale + psum;

        c0.x *= scale; c0.y *= scale; c0.z *= scale; c0.w *= scale;
        c1.x *= scale; c1.y *= scale; c1.z *= scale; c1.w *= scale;
        c2.x *= scale; c2.y *= scale; c2.z *= scale; c2.w *= scale;
        c3.x *= scale; c3.y *= scale; c3.z *= scale; c3.w *= scale;
        #pragma unroll
        for (int c = 0; c < CHUNK; ++c) {
            c0.x += p[c] * r[c][0].x;  c0.y += p[c] * r[c][0].y;
            c0.z += p[c] * r[c][0].z;  c0.w += p[c] * r[c][0].w;
            c1.x += p[c] * r[c][1].x;  c1.y += p[c] * r[c][1].y;
            c1.z += p[c] * r[c][1].z;  c1.w += p[c] * r[c][1].w;
            c2.x += p[c] * r[c][2].x;  c2.y += p[c] * r[c][2].y;
            c2.z += p[c] * r[c][2].z;  c2.w += p[c] * r[c][2].w;
            c3.x += p[c] * r[c][3].x;  c3.y += p[c] * r[c][3].y;
            c3.z += p[c] * r[c][3].z;  c3.w += p[c] * r[c][3].w;
        }
        m = newm;
    }

    // coalesced raw-score store: lane r (r<32) holds score of row row0+r
    if (lane < ROWS_PER_WAVE)
        scores[(size_t)b * S_ + row0 + lane] = myscore;

    // combine the 4 waves of this block in LDS
    __shared__ float lds_ctx[NWAVE][H_];   // 16 KB
    __shared__ float lds_m[NWAVE];
    __shared__ float lds_l[NWAVE];
    float4* dst = (float4*)lds_ctx[wave];
    dst[lane]       = c0;
    dst[lane + 64]  = c1;
    dst[lane + 128] = c2;
    dst[lane + 192] = c3;
    if (lane == 0) { lds_m[wave] = m; lds_l[wave] = l; }
    __syncthreads();

    const float M  = fmaxf(fmaxf(lds_m[0], lds_m[1]), fmaxf(lds_m[2], lds_m[3]));
    const float w0 = __expf(lds_m[0] - M);
    const float w1 = __expf(lds_m[1] - M);
    const float w2 = __expf(lds_m[2] - M);
    const float w3 = __expf(lds_m[3] - M);

    const int e = tid * 4;                 // 256 threads x 4 = 1024 elems
    const float4 a0 = *(const float4*)&lds_ctx[0][e];
    const float4 a1 = *(const float4*)&lds_ctx[1][e];
    const float4 a2 = *(const float4*)&lds_ctx[2][e];
    const float4 a3 = *(const float4*)&lds_ctx[3][e];
    float4 o;
    o.x = a0.x * w0 + a1.x * w1 + a2.x * w2 + a3.x * w3;
    o.y = a0.y * w0 + a1.y * w1 + a2.y * w2 + a3.y * w3;
    o.z = a0.z * w0 + a1.z * w1 + a2.z * w2 + a3.z * w3;
    o.w = a0.w * w0 + a1.w * w1 + a2.w * w2 + a3.w * w3;
    *(float4*)&part_ctx[(size_t)blk * H_ + e] = o;

    if (tid == 0) {
        const float L = lds_l[0] * w0 + lds_l[1] * w1 + lds_l[2] * w2 + lds_l[3] * w3;
        part_ml[blk * 2]     = M;
        part_ml[blk * 2 + 1] = L;
    }
}

// Pass 2: combine NBLK partials per batch; write context; normalize the
// raw scores in d_out into attn (in place). grid = (B, 5):
// y==0 -> context; y in 1..4 -> attn quarter-chunks of 1024.
__global__ __launch_bounds__(256) void attn_pass2(
    const float* __restrict__ part_ctx,  // [B*NBLK, H]
    const float* __restrict__ part_ml,   // [B*NBLK, 2]
    float* __restrict__ out_ctx,         // [B,H]
    float* __restrict__ attn)            // [B,S], holds raw scores on entry
{
    const int b    = blockIdx.x;
    const int part = blockIdx.y;
    const int tid  = threadIdx.x;

    float M = -INFINITY;
    #pragma unroll
    for (int p = 0; p < NBLK; ++p)
        M = fmaxf(M, part_ml[(b * NBLK + p) * 2]);

    float L = 0.0f;
    float w[NBLK];
    #pragma unroll
    for (int p = 0; p < NBLK; ++p) {
        w[p] = __expf(part_ml[(b * NBLK + p) * 2] - M);
        L += part_ml[(b * NBLK + p) * 2 + 1] * w[p];
    }
    const float invL = 1.0f / L;

    if (part == 0) {
        const int e = tid * 4;
        float4 acc = {0.f, 0.f, 0.f, 0.f};
        #pragma unroll
        for (int p = 0; p < NBLK; ++p) {
            const float4 v = *(const float4*)&part_ctx[(size_t)(b * NBLK + p) * H_ + e];
            acc.x += v.x * w[p];  acc.y += v.y * w[p];
            acc.z += v.z * w[p];  acc.w += v.w * w[p];
        }
        acc.x *= invL; acc.y *= invL; acc.z *= invL; acc.w *= invL;
        *(float4*)&out_ctx[(size_t)b * H_ + e] = acc;
    } else {
        const size_t s0 = (size_t)b * S_ + (size_t)(part - 1) * 1024 + tid * 4;
        float4 sc = *(const float4*)&attn[s0];
        sc.x = __expf(sc.x - M) * invL;
        sc.y = __expf(sc.y - M) * invL;
        sc.z = __expf(sc.z - M) * invL;
        sc.w = __expf(sc.w - M) * invL;
        *(float4*)&attn[s0] = sc;
    }
}

extern "C" void kernel_launch(void* const* d_in, const int* in_sizes, int n_in,
                              void* d_out, int out_size, void* d_ws, size_t ws_size,
                              hipStream_t stream) {
    (void)in_sizes; (void)n_in; (void)out_size; (void)ws_size;
    const float* hidden = (const float*)d_in[0];  // [2,B,H]
    const float* enc    = (const float*)d_in[1];  // [B,S,H]
    const int*   mask   = (const int*)d_in[2];    // [B,S]

    float* out      = (float*)d_out;
    float* out_ctx  = out;                        // [B,H]
    float* attn     = out + (size_t)B_ * H_;      // [B,S]

    float* part_ctx = (float*)d_ws;                        // B*NBLK*H floats (4 MB)
    float* part_ml  = part_ctx + (size_t)B_ * NBLK * H_;   // B*NBLK*2 floats

    attn_pass1<<<dim3(B_ * NBLK), dim3(256), 0, stream>>>(
        hidden, enc, mask, attn, part_ctx, part_ml);
    attn_pass2<<<dim3(B_, 5), dim3(256), 0, stream>>>(
        part_ctx, part_ml, out_ctx, attn);
}